// Round 1
// baseline (369.825 us; speedup 1.0000x reference)
//
#include <hip/hip_runtime.h>
#include <stdint.h>

// ---------------------------------------------------------------------------
// Encoder block, MI355X bf16-MFMA implementation (round 0: correctness-first)
//   x:[8,1024,768] f32.  Quirks preserved: k = q (query projection), scale=768^-0.5.
// Pipeline:
//   repack -> LN1 -> GEMM_QV (q row-major, v transposed [B,H,E,S]) ->
//   attention (S^T orientation, online softmax) -> GEMM_O (+x residual -> d_out) ->
//   LN2 -> GEMM_FC1 (gelu) -> GEMM_FC2 (+d_out residual in place)
// ---------------------------------------------------------------------------

typedef __attribute__((ext_vector_type(8))) short s8v;      // 8 x bf16 (4 VGPR)
typedef __attribute__((ext_vector_type(4))) float f32x4;    // MFMA C/D frag
typedef __attribute__((ext_vector_type(4))) unsigned short us4v;

__device__ __forceinline__ unsigned short f2b(float f) {  // f32 -> bf16 RTNE
  union { float f; unsigned u; } v; v.f = f;
  unsigned r = v.u + 0x7FFFu + ((v.u >> 16) & 1u);
  return (unsigned short)(r >> 16);
}

// ---------------- weight repack: all weights -> bf16, B^T [N][K] layout ------
__global__ __launch_bounds__(256) void repack_kernel(
    const float* __restrict__ Wq, const float* __restrict__ bq,
    const float* __restrict__ Wv, const float* __restrict__ bv,
    const float* __restrict__ Wo, const float* __restrict__ W1,
    const float* __restrict__ W2,
    unsigned short* __restrict__ Wqv_t, float* __restrict__ bias_qv,
    unsigned short* __restrict__ Wo_t, unsigned short* __restrict__ W1_t,
    unsigned short* __restrict__ W2_t)
{
  int i = blockIdx.x * 256 + threadIdx.x;
  // Wqv_t [1536][768]: rows 0..767 = q cols (h*64+e), 768..1535 = v cols
  if (i < 1536 * 768) {
    int n = i / 768, d = i % 768;
    float val;
    if (n < 768) { int h = n >> 6, e = n & 63; val = Wq[(h * 768 + d) * 64 + e]; }
    else { int c = n - 768; int h = c >> 6, e = c & 63; val = Wv[(h * 768 + d) * 64 + e]; }
    Wqv_t[i] = f2b(val);
  }
  if (i < 1536) bias_qv[i] = (i < 768) ? bq[i] : bv[i - 768];
  if (i < 768 * 768)  { int n = i / 768,  k = i % 768;  Wo_t[i] = f2b(Wo[k * 768  + n]); }
  if (i < 3072 * 768) { int n = i / 768,  k = i % 768;  W1_t[i] = f2b(W1[k * 3072 + n]); }
  if (i < 768 * 3072) { int n = i / 3072, k = i % 3072; W2_t[i] = f2b(W2[k * 768  + n]); }
}

// ---------------- LayerNorm: f32 [8192][768] -> bf16 ------------------------
__global__ __launch_bounds__(256) void ln_kernel(
    const float* __restrict__ x, const float* __restrict__ g,
    const float* __restrict__ b, unsigned short* __restrict__ out)
{
  __shared__ float red[4], red2[4];
  int row = blockIdx.x, t = threadIdx.x;
  const float* xr = x + (size_t)row * 768;
  float v0 = xr[t], v1 = xr[t + 256], v2 = xr[t + 512];
  float s = v0 + v1 + v2;
  #pragma unroll
  for (int m = 32; m; m >>= 1) s += __shfl_xor(s, m);
  if ((t & 63) == 0) red[t >> 6] = s;
  __syncthreads();
  float mean = (red[0] + red[1] + red[2] + red[3]) * (1.f / 768.f);
  float d0 = v0 - mean, d1 = v1 - mean, d2 = v2 - mean;
  float vs = d0 * d0 + d1 * d1 + d2 * d2;
  #pragma unroll
  for (int m = 32; m; m >>= 1) vs += __shfl_xor(vs, m);
  if ((t & 63) == 0) red2[t >> 6] = vs;
  __syncthreads();
  float var = (red2[0] + red2[1] + red2[2] + red2[3]) * (1.f / 768.f);
  float rs = rsqrtf(var + 1e-5f);
  unsigned short* o = out + (size_t)row * 768;
  o[t]       = f2b(d0 * rs * g[t]       + b[t]);
  o[t + 256] = f2b(d1 * rs * g[t + 256] + b[t + 256]);
  o[t + 512] = f2b(d2 * rs * g[t + 512] + b[t + 512]);
}

// ---------------- GEMM: C[M,N] = A[M,K](bf16) * Bt[N,K]^T(bf16) + bias -------
// 128x128 tile, BK=64, 4 waves (2x2), each wave 64x64 via 4x4 mfma_16x16x32_bf16.
// EPI: 1 = f32 out = resid + acc + bias   (resid may alias out)
//      2 = bf16 out = gelu(acc + bias)
//      3 = qv split: cols<768 -> q_out [M][768]; cols>=768 -> v transposed [B,H,E,S]
#define BKP 72   // 64 + 8 pad: row stride 144B = 9x16B -> conflict-free b128
template<int EPI>
__global__ __launch_bounds__(256) void gemm_kernel(
    const unsigned short* __restrict__ A, const unsigned short* __restrict__ Bt,
    const float* __restrict__ bias,
    const float* resid, float* out_f32,
    unsigned short* __restrict__ out_bf,
    unsigned short* __restrict__ q_out, unsigned short* __restrict__ vt_out,
    int M, int N, int K)
{
  __shared__ unsigned short As[128][BKP];
  __shared__ unsigned short Bs[128][BKP];
  int nt = N >> 7;
  int m0 = (blockIdx.x / nt) << 7;
  int n0 = (blockIdx.x % nt) << 7;
  int t = threadIdx.x, lane = t & 63, w = t >> 6;
  int l15 = lane & 15, lg = lane >> 4;
  int wm = (w >> 1) << 6, wn = (w & 1) << 6;
  f32x4 acc[4][4] = {};
  for (int k0 = 0; k0 < K; k0 += 64) {
    __syncthreads();
    #pragma unroll
    for (int i = 0; i < 4; ++i) {            // 1024 chunks of 8 bf16 per operand
      int chunk = t + (i << 8);
      int r = chunk >> 3, c8 = (chunk & 7) << 3;
      *(s8v*)&As[r][c8] = *(const s8v*)&A [(size_t)(m0 + r) * K + k0 + c8];
      *(s8v*)&Bs[r][c8] = *(const s8v*)&Bt[(size_t)(n0 + r) * K + k0 + c8];
    }
    __syncthreads();
    #pragma unroll
    for (int kk = 0; kk < 2; ++kk) {
      s8v a[4], b[4];
      #pragma unroll
      for (int i = 0; i < 4; ++i) {
        a[i] = *(const s8v*)&As[wm + i * 16 + l15][kk * 32 + lg * 8];
        b[i] = *(const s8v*)&Bs[wn + i * 16 + l15][kk * 32 + lg * 8];
      }
      #pragma unroll
      for (int mi = 0; mi < 4; ++mi)
        #pragma unroll
        for (int ni = 0; ni < 4; ++ni)
          acc[mi][ni] = __builtin_amdgcn_mfma_f32_16x16x32_bf16(a[mi], b[ni], acc[mi][ni], 0, 0, 0);
    }
  }
  #pragma unroll
  for (int mi = 0; mi < 4; ++mi) {
    #pragma unroll
    for (int ni = 0; ni < 4; ++ni) {
      int col = n0 + wn + ni * 16 + l15;
      float bs = bias[col];
      #pragma unroll
      for (int r = 0; r < 4; ++r) {
        int row = m0 + wm + mi * 16 + lg * 4 + r;   // C/D: col=lane&15, row=(lane>>4)*4+reg
        float v = acc[mi][ni][r] + bs;
        if (EPI == 1) {
          out_f32[(size_t)row * N + col] = resid[(size_t)row * N + col] + v;
        } else if (EPI == 2) {
          float gl = 0.5f * v * (1.f + erff(v * 0.70710678118654752f));
          out_bf[(size_t)row * N + col] = f2b(gl);
        } else { // EPI == 3
          if (col < 768) {
            q_out[(size_t)row * 768 + col] = f2b(v);
          } else {
            int c = col - 768; int hh = c >> 6, e = c & 63;
            int bb = row >> 10, s = row & 1023;
            vt_out[(((size_t)(bb * 12 + hh)) * 64 + e) * 1024 + s] = f2b(v);
          }
        }
      }
    }
  }
}

// ---------------- fused attention (k = q quirk, scale = 768^-0.5) ------------
// grid: 96 (b,h) x 8 q-tiles of 128.  4 waves; wave owns 32 q-columns.
// S^T = K*Q^T  (rows=keys, cols=q)  -> softmax stats lane-local per q-col.
// PV as o^T = V^T * P^T with V staged [E][KT] from v_t[B,H,E,S].
__global__ __launch_bounds__(256) void attn_kernel(
    const unsigned short* __restrict__ qk,  // [8192][768] (q == k)
    const unsigned short* __restrict__ vt,  // [96][64][1024]
    unsigned short* __restrict__ o)         // [8192][768]
{
  __shared__ unsigned short Qs[128][BKP];
  __shared__ unsigned short Ks[64][BKP];
  __shared__ unsigned short Vt[64][BKP];
  __shared__ unsigned short Ps[128][BKP];
  int qt = blockIdx.x & 7, bh = blockIdx.x >> 3;
  int b = bh / 12, h = bh % 12;
  int t = threadIdx.x, lane = t & 63, w = t >> 6;
  int l15 = lane & 15, lg = lane >> 4;
  int wq0 = w << 5;
  size_t qrow0 = (size_t)b * 1024 + qt * 128;
  size_t krow0 = (size_t)b * 1024;
  size_t vbase = ((size_t)bh) * 64 * 1024;
  const float scale = 0.03608439182435161f;  // 768^-0.5 (full d_k quirk)

  #pragma unroll
  for (int i = 0; i < 4; ++i) {
    int chunk = t + (i << 8); int r = chunk >> 3, c8 = (chunk & 7) << 3;
    *(s8v*)&Qs[r][c8] = *(const s8v*)&qk[(qrow0 + r) * 768 + h * 64 + c8];
  }
  f32x4 oacc[4][2] = {};
  float mrun[2] = {-1e30f, -1e30f};
  float lrun[2] = {0.f, 0.f};

  for (int kt = 0; kt < 16; ++kt) {
    __syncthreads();
    #pragma unroll
    for (int i = 0; i < 2; ++i) {
      int chunk = t + (i << 8); int r = chunk >> 3, c8 = (chunk & 7) << 3;
      *(s8v*)&Ks[r][c8] = *(const s8v*)&qk[(krow0 + kt * 64 + r) * 768 + h * 64 + c8];
      *(s8v*)&Vt[r][c8] = *(const s8v*)&vt[vbase + (size_t)r * 1024 + kt * 64 + c8];
    }
    __syncthreads();
    // S^T frags [4 kmi][2 ni]
    f32x4 st[4][2] = {};
    #pragma unroll
    for (int kk = 0; kk < 2; ++kk) {
      s8v a[4], bqf[2];
      #pragma unroll
      for (int i = 0; i < 4; ++i) a[i] = *(const s8v*)&Ks[i * 16 + l15][kk * 32 + lg * 8];
      #pragma unroll
      for (int i = 0; i < 2; ++i) bqf[i] = *(const s8v*)&Qs[wq0 + i * 16 + l15][kk * 32 + lg * 8];
      #pragma unroll
      for (int mi = 0; mi < 4; ++mi)
        #pragma unroll
        for (int ni = 0; ni < 2; ++ni)
          st[mi][ni] = __builtin_amdgcn_mfma_f32_16x16x32_bf16(a[mi], bqf[ni], st[mi][ni], 0, 0, 0);
    }
    // online softmax per q-column (col = wq0 + ni*16 + l15)
    #pragma unroll
    for (int ni = 0; ni < 2; ++ni) {
      float cm = -1e30f;
      #pragma unroll
      for (int mi = 0; mi < 4; ++mi)
        #pragma unroll
        for (int r = 0; r < 4; ++r) cm = fmaxf(cm, st[mi][ni][r]);
      cm = fmaxf(cm, __shfl_xor(cm, 16));
      cm = fmaxf(cm, __shfl_xor(cm, 32));
      float pm = cm * scale;
      float mnew = fmaxf(mrun[ni], pm);
      float fac = __expf(mrun[ni] - mnew);
      float psum = 0.f;
      int qrow = wq0 + ni * 16 + l15;
      #pragma unroll
      for (int mi = 0; mi < 4; ++mi) {
        us4v pb;
        #pragma unroll
        for (int r = 0; r < 4; ++r) {
          float p = __expf(st[mi][ni][r] * scale - mnew);
          psum += p;
          pb[r] = f2b(p);
        }
        *(us4v*)&Ps[qrow][mi * 16 + lg * 4] = pb;   // 4 consecutive keys, 8B store
      }
      psum += __shfl_xor(psum, 16);
      psum += __shfl_xor(psum, 32);
      lrun[ni] = lrun[ni] * fac + psum;
      mrun[ni] = mnew;
      #pragma unroll
      for (int ei = 0; ei < 4; ++ei) oacc[ei][ni] *= fac;
    }
    __syncthreads();
    // PV: o^T += V^T * P^T   frags [4 ei][2 ni]
    #pragma unroll
    for (int kk = 0; kk < 2; ++kk) {
      s8v a[4], bp[2];
      #pragma unroll
      for (int i = 0; i < 4; ++i) a[i] = *(const s8v*)&Vt[i * 16 + l15][kk * 32 + lg * 8];
      #pragma unroll
      for (int i = 0; i < 2; ++i) bp[i] = *(const s8v*)&Ps[wq0 + i * 16 + l15][kk * 32 + lg * 8];
      #pragma unroll
      for (int ei = 0; ei < 4; ++ei)
        #pragma unroll
        for (int ni = 0; ni < 2; ++ni)
          oacc[ei][ni] = __builtin_amdgcn_mfma_f32_16x16x32_bf16(a[ei], bp[ni], oacc[ei][ni], 0, 0, 0);
    }
  }
  // write o[q][e], e from rows of o^T: 4 consecutive e per frag -> 8B stores
  #pragma unroll
  for (int ni = 0; ni < 2; ++ni) {
    float inv = 1.f / lrun[ni];
    int q = wq0 + ni * 16 + l15;
    size_t obase = (qrow0 + q) * 768 + h * 64;
    #pragma unroll
    for (int ei = 0; ei < 4; ++ei) {
      us4v ov;
      #pragma unroll
      for (int r = 0; r < 4; ++r) ov[r] = f2b(oacc[ei][ni][r] * inv);
      *(us4v*)&o[obase + ei * 16 + lg * 4] = ov;
    }
  }
}

// ---------------------------------------------------------------------------
extern "C" void kernel_launch(void* const* d_in, const int* in_sizes, int n_in,
                              void* d_out, int out_size, void* d_ws, size_t ws_size,
                              hipStream_t stream)
{
  const float* x     = (const float*)d_in[0];
  const float* ln1_g = (const float*)d_in[1];
  const float* ln1_b = (const float*)d_in[2];
  const float* Wq    = (const float*)d_in[3];
  const float* bq    = (const float*)d_in[4];
  const float* Wv    = (const float*)d_in[5];
  const float* bv    = (const float*)d_in[6];
  const float* Wo    = (const float*)d_in[7];
  const float* bo    = (const float*)d_in[8];
  const float* ln2_g = (const float*)d_in[9];
  const float* ln2_b = (const float*)d_in[10];
  const float* W1    = (const float*)d_in[11];
  const float* b1    = (const float*)d_in[12];
  const float* W2    = (const float*)d_in[13];
  const float* b2    = (const float*)d_in[14];
  float* out = (float*)d_out;

  char* ws = (char*)d_ws;
  size_t off = 0;
  auto alloc = [&](size_t bytes) -> void* {
    void* p = ws + off; off += (bytes + 255) & ~(size_t)255; return p;
  };
  unsigned short* Wqv_t  = (unsigned short*)alloc(1536ull * 768 * 2);
  float*          bias_qv= (float*)         alloc(1536ull * 4);
  unsigned short* Wo_t   = (unsigned short*)alloc(768ull * 768 * 2);
  unsigned short* W1_t   = (unsigned short*)alloc(3072ull * 768 * 2);
  unsigned short* W2_t   = (unsigned short*)alloc(768ull * 3072 * 2);
  unsigned short* h_bf   = (unsigned short*)alloc(8192ull * 768 * 2);
  unsigned short* q_bf   = (unsigned short*)alloc(8192ull * 768 * 2);
  unsigned short* v_t    = (unsigned short*)alloc(96ull * 64 * 1024 * 2);
  unsigned short* o_bf   = (unsigned short*)alloc(8192ull * 768 * 2);
  unsigned short* h2_bf  = (unsigned short*)alloc(8192ull * 768 * 2);
  unsigned short* m1_bf  = (unsigned short*)alloc(8192ull * 3072 * 2);
  // total ~127 MB

  repack_kernel<<<9216, 256, 0, stream>>>(Wq, bq, Wv, bv, Wo, W1, W2,
                                          Wqv_t, bias_qv, Wo_t, W1_t, W2_t);
  ln_kernel<<<8192, 256, 0, stream>>>(x, ln1_g, ln1_b, h_bf);
  gemm_kernel<3><<<768, 256, 0, stream>>>(h_bf, Wqv_t, bias_qv, nullptr, nullptr,
                                          nullptr, q_bf, v_t, 8192, 1536, 768);
  attn_kernel<<<768, 256, 0, stream>>>(q_bf, v_t, o_bf);
  gemm_kernel<1><<<384, 256, 0, stream>>>(o_bf, Wo_t, bo, x, out,
                                          nullptr, nullptr, nullptr, 8192, 768, 768);
  ln_kernel<<<8192, 256, 0, stream>>>(out, ln2_g, ln2_b, h2_bf);
  gemm_kernel<2><<<1536, 256, 0, stream>>>(h2_bf, W1_t, b1, nullptr, nullptr,
                                           m1_bf, nullptr, nullptr, 8192, 3072, 768);
  gemm_kernel<1><<<384, 256, 0, stream>>>(m1_bf, W2_t, b2, out, out,
                                          nullptr, nullptr, nullptr, 8192, 768, 3072);
}